// Round 12
// baseline (203.026 us; speedup 1.0000x reference)
//
#include <hip/hip_runtime.h>
#include <hip/hip_bf16.h>

namespace {
enum : int {
  CIN = 64, CMID = 32, COUT = 64,
  H = 128, W = 48, HW = H * W,          // 6144
  QSSZ = CMID * HW,                     // 196608 floats
  // attention tiling
  QPT = 4,                              // queries per lane
  QG  = 64 * QPT,                       // 256 queries per block
  NQG = 12,                             // 3072/256 query groups per n
  KVW = 180,                            // kv elems per wave
  SG  = 8,                              // slice groups (8*4*180 = 5760)
  KVLEN = 5760,
  PARTSZ = 16 * NQG * SG * QG * 5,      // 1,966,080 floats
  KVISZ = 16 * KVLEN * 8,               // 737,280 floats (packed k4|v4)
  CIGQ = 4, CIGO = 4,
};
}

__device__ __forceinline__ float fexp2(float x) { return __builtin_amdgcn_exp2f(x); }

// ---------------------------------------------------------------------------
// Kernel 1 (verified round 7-9): q/k/v 3x3 convs, ci split 4-ways, weights
// in LDS stride 145 (conflict-free). grid (128,2,4) x 192.
// ---------------------------------------------------------------------------
__global__ __launch_bounds__(192) void qkv_conv_kernel(
    const float* __restrict__ x,
    const float* __restrict__ wq, const float* __restrict__ wk,
    const float* __restrict__ wv, float* __restrict__ qpart)
{
  __shared__ float ws[48 * 145];                 // 27840 B
  __shared__ alignas(16) float xs[3 * 16 * 52];  // 9984 B
  const int y = blockIdx.x;
  const int half = blockIdx.y;
  const int cig = blockIdx.z;          // 16 ci per group
  const int tid = threadIdx.x;
  for (int idx = tid; idx < 3 * 16 * 50; idx += 192) {
    int ky = idx / (16 * 50);
    int r = idx - ky * (16 * 50);
    int cil = r / 50;
    int xx = r - cil * 50;
    int gy = y + ky - 1;
    int gx = xx - 1;
    float v = 0.0f;
    if (gy >= 0 && gy < H && (unsigned)gx < (unsigned)W)
      v = x[(cig * 16 + cil) * HW + gy * W + gx];
    xs[(ky * 16 + cil) * 52 + xx] = v;
  }
  for (int idx = tid; idx < 48 * 144; idx += 192) {
    const int cl_loc = idx / 144;
    const int e = idx - cl_loc * 144;     // ci_local*9 + tap
    const int cog = half * 48 + cl_loc;
    const int t = cog >> 5;
    const int cl = cog & 31;
    const float* wsel = (t == 0) ? wq : (t == 1) ? wk : wv;
    ws[cl_loc * 145 + e] = wsel[cl * (CIN * 9) + cig * 144 + e];
  }
  __syncthreads();

  const int col = tid >> 2;        // 0..47
  const int xg = tid & 3;          // 0..3
  const int cog = half * 48 + col;
  const float* wrowb = &ws[col * 145];

  float acc[12];
#pragma unroll
  for (int i = 0; i < 12; ++i) acc[i] = 0.0f;

#pragma unroll 4
  for (int cil = 0; cil < 16; ++cil) {
#pragma unroll
    for (int ky = 0; ky < 3; ++ky) {
      const float4* p4 =
          reinterpret_cast<const float4*>(&xs[(ky * 16 + cil) * 52 + xg * 12]);
      float4 r0 = p4[0], r1 = p4[1], r2 = p4[2], r3 = p4[3];
      float xr[16] = {r0.x, r0.y, r0.z, r0.w, r1.x, r1.y, r1.z, r1.w,
                      r2.x, r2.y, r2.z, r2.w, r3.x, r3.y, r3.z, r3.w};
      const float* wr = wrowb + cil * 9 + ky * 3;
#pragma unroll
      for (int kx = 0; kx < 3; ++kx) {
        float wgt = wr[kx];
#pragma unroll
        for (int xx = 0; xx < 12; ++xx)
          acc[xx] = fmaf(wgt, xr[xx + kx], acc[xx]);
      }
    }
  }

  const int x0 = xg * 12;
  float* dst = &qpart[(size_t)(cig * 96 + cog) * HW + y * W + x0];
#pragma unroll
  for (int xx = 0; xx < 12; ++xx) dst[xx] = acc[xx];
}

// ---------------------------------------------------------------------------
// Kernel 1b (verified round 7-9): reduce 4 ci-partials, apply bias (+ exp2
// scale for q), write q_s / k_s / v_s. float4 per thread.
// ---------------------------------------------------------------------------
__global__ __launch_bounds__(256) void qkv_reduce_kernel(
    const float* __restrict__ qpart,
    const float* __restrict__ bq, const float* __restrict__ bk,
    const float* __restrict__ bv,
    float* __restrict__ q_s, float* __restrict__ k_s, float* __restrict__ v_s)
{
  const int fidx = blockIdx.x * 256 + threadIdx.x;  // 0..147455 (96ch*1536)
  const int cog = fidx / 1536;
  const int p4 = fidx - cog * 1536;
  const float4* src = reinterpret_cast<const float4*>(qpart) + cog * 1536 + p4;
  float4 s = src[0];
  const float4 s1 = src[96 * 1536], s2 = src[2 * 96 * 1536], s3 = src[3 * 96 * 1536];
  s.x += s1.x + s2.x + s3.x;
  s.y += s1.y + s2.y + s3.y;
  s.z += s1.z + s2.z + s3.z;
  s.w += s1.w + s2.w + s3.w;

  const int cl = cog & 31;
  if (cog < 32) {
    const float b = bq[cl];
    const float c = 0.7213475204444817f;   // 0.5 * log2(e)
    float4 o = {(s.x + b) * c, (s.y + b) * c, (s.z + b) * c, (s.w + b) * c};
    reinterpret_cast<float4*>(q_s)[cl * 1536 + p4] = o;
  } else {
    const float b = (cog < 64) ? bk[cl] : bv[cl];
    float* dst = (cog < 64) ? k_s : v_s;
    float4 o = {s.x + b, s.y + b, s.z + b, s.w + b};
    reinterpret_cast<float4*>(dst)[cl * 1536 + p4] = o;
  }
}

// ---------------------------------------------------------------------------
// Kernel 1c (verified round 7-9): materialize the as_strided flange gather
// into packed kvi[n][m] = {k4, v4}. grid (45,16) x 128.
// ---------------------------------------------------------------------------
__global__ __launch_bounds__(128) void kv_pack_kernel(
    const float* __restrict__ k_s, const float* __restrict__ v_s,
    float4* __restrict__ kvi)
{
  const int m = blockIdx.x * 128 + threadIdx.x;   // 0..5759
  const int n = blockIdx.y;
  const int h = n >> 1;
  const int j = n & 1;
  const int m0 = m / 40;
  const int m1 = m - m0 * 40;
  const int base = h * 24576 + j * 24 + m0 * 48 + m1;
  float k4[4], v4[4];
#pragma unroll
  for (int d = 0; d < 4; ++d) {
    const int F = base + d * 6144;       // flat idx into (32,144,64) view
    const int c = F / 9216;
    const int rem = F - c * 9216;
    const int yy = rem >> 6;
    const int xx = rem & 63;
    const bool ok = (yy >= 8 && yy < 136 && xx >= 8 && xx < 56);
    const int src = c * HW + (yy - 8) * W + (xx - 8);
    k4[d] = ok ? k_s[src] : 0.0f;
    v4[d] = ok ? v_s[src] : 0.0f;
  }
  const size_t o = ((size_t)n * KVLEN + m) * 2;
  kvi[o + 0] = make_float4(k4[0], k4[1], k4[2], k4[3]);
  kvi[o + 1] = make_float4(v4[0], v4[1], v4[2], v4[3]);
}

// ---------------------------------------------------------------------------
// Kernel 2 (NEW this round — only changed kernel): attention with SGPR-fed
// kv. kvn base is wave-uniform (readfirstlane) so chunk loads compile to
// s_load_dwordx4 into SGPRs; named A/B double buffer (4 kv per chunk) hides
// scalar-load latency under ~640 cyc of VALU per chunk. Scalar fp32 math
// (verified in round 6), exp2-domain softmax, fixed -16 bias, additive
// partials. LDS = 20KB merge buffer only -> 6 blocks/CU = 24 waves/CU.
// grid 1536 flat, XCD-swizzled (2 n per XCD). 45 chunks: 22 dbuf iters +
// 1 tail; all loads strictly in-slice (no OOB).
// ---------------------------------------------------------------------------
__global__ __launch_bounds__(256, 4) void attn_kernel(
    const float* __restrict__ q_s, const float4* __restrict__ kvi4,
    float* __restrict__ part)
{
  __shared__ float smem[4 * QG * 5];   // 20480 B
  const int tid = threadIdx.x;
  const int lane = tid & 63;
  const int wu = __builtin_amdgcn_readfirstlane(tid >> 6);
  const int bid = blockIdx.x;          // 0..1535
  const int xcd = bid & 7;
  const int li = bid >> 3;             // 0..191
  const int hi2 = li >= 96 ? 1 : 0;
  const int n = xcd * 2 + hi2;
  const int r = li - hi2 * 96;         // 0..95
  const int qgrp = r % 12;
  const int sgrp = r / 12;             // 0..7
  const int h = n >> 1, j = n & 1;

  float qr[4][4];
#pragma unroll
  for (int qi = 0; qi < 4; ++qi) {
    const int qg = qgrp * QG + qi * 64 + lane;
    const int q0 = qg / 24;
    const int q1 = qg - q0 * 24;
    const int qoff = q0 * W + j * 24 + q1;
#pragma unroll
    for (int d = 0; d < 4; ++d)
      qr[qi][d] = q_s[(h * 4 + d) * HW + qoff];
  }

  const float4* kvn = kvi4 + ((size_t)n * KVLEN + (sgrp * 4 + wu) * KVW) * 2;

  float lsum[4] = {0.0f, 0.0f, 0.0f, 0.0f};
  float ac[4][4];
#pragma unroll
  for (int qi = 0; qi < 4; ++qi)
#pragma unroll
    for (int d = 0; d < 4; ++d) ac[qi][d] = 0.0f;

  auto compute4 = [&](float4 (&C)[8]) {
#pragma unroll
    for (int kv = 0; kv < 4; ++kv) {
      const float4 k4 = C[2 * kv];
      const float4 v4 = C[2 * kv + 1];
#pragma unroll
      for (int qi = 0; qi < 4; ++qi) {
        float s = fmaf(qr[qi][0], k4.x,
                  fmaf(qr[qi][1], k4.y,
                  fmaf(qr[qi][2], k4.z,
                  fmaf(qr[qi][3], k4.w, -16.0f))));
        const float p = fexp2(s);
        lsum[qi] += p;
        ac[qi][0] = fmaf(p, v4.x, ac[qi][0]);
        ac[qi][1] = fmaf(p, v4.y, ac[qi][1]);
        ac[qi][2] = fmaf(p, v4.z, ac[qi][2]);
        ac[qi][3] = fmaf(p, v4.w, ac[qi][3]);
      }
    }
  };

  // 180 kv = 45 chunks of 4. Preload chunk0; 22 dbuf iters cover chunks
  // 0..43; tail computes chunk 44. All loads within the 360-float4 slice.
  float4 A[8], B[8];
#pragma unroll
  for (int i = 0; i < 8; ++i) A[i] = kvn[i];
  int off = 8;
#pragma unroll 1
  for (int it = 0; it < 22; ++it) {
#pragma unroll
    for (int i = 0; i < 8; ++i) B[i] = kvn[off + i];
    compute4(A);
#pragma unroll
    for (int i = 0; i < 8; ++i) A[i] = kvn[off + 8 + i];
    compute4(B);
    off += 16;
  }
  compute4(A);   // chunk 44

  // merge 4 waves' partials -> one set, write to part
#pragma unroll
  for (int qi = 0; qi < 4; ++qi) {
    float* mb = &smem[wu * (QG * 5) + qi * 5 * 64 + lane];
    mb[0]   = lsum[qi];
    mb[64]  = ac[qi][0];
    mb[128] = ac[qi][1];
    mb[192] = ac[qi][2];
    mb[256] = ac[qi][3];
  }
  __syncthreads();
  float* pout = part + (size_t)((n * NQG + qgrp) * SG + sgrp) * (QG * 5);
  for (int id = tid; id < QG * 5; id += 256)
    pout[id] = smem[id] + smem[QG * 5 + id] + smem[2 * QG * 5 + id] +
               smem[3 * QG * 5 + id];
}

// ---------------------------------------------------------------------------
// Kernel 2b: merge SG slice-group partials + normalize -> o_mid.
// grid (12,16) x 256; thread = one query. (Round-9 logic, QPT=4 indexing.)
// ---------------------------------------------------------------------------
__global__ __launch_bounds__(256) void merge_kernel(
    const float* __restrict__ part, float* __restrict__ o_mid)
{
  const int tid = threadIdx.x;
  const int qi = tid >> 6;      // 0..3
  const int lane = tid & 63;
  const int qgrp = blockIdx.x;
  const int n = blockIdx.y;
  const int h = n >> 1;
  const int j = n & 1;

  const float* pb = part + (size_t)((n * NQG + qgrp) * SG) * (QG * 5) +
                    qi * 5 * 64 + lane;
  float L = 0.0f, A0 = 0.0f, A1 = 0.0f, A2 = 0.0f, A3 = 0.0f;
#pragma unroll
  for (int s = 0; s < SG; ++s) {
    const float* p = pb + s * (QG * 5);
    L  += p[0];
    A0 += p[64];
    A1 += p[128];
    A2 += p[192];
    A3 += p[256];
  }
  const float inv = 1.0f / L;
  const int qg = qgrp * QG + qi * 64 + lane;
  const int q0 = qg / 24;
  const int q1 = qg - q0 * 24;
  const int qoff = q0 * W + j * 24 + q1;
  o_mid[(h * 4 + 0) * HW + qoff] = A0 * inv;
  o_mid[(h * 4 + 1) * HW + qoff] = A1 * inv;
  o_mid[(h * 4 + 2) * HW + qoff] = A2 * inv;
  o_mid[(h * 4 + 3) * HW + qoff] = A3 * inv;
}

// ---------------------------------------------------------------------------
// Kernel 3 (verified round 7-9): output 3x3 conv, ci split 4-ways, weights
// in LDS stride 73 (conflict-free). grid (128,2,4) x 128.
// ---------------------------------------------------------------------------
__global__ __launch_bounds__(128) void out_conv_kernel(
    const float* __restrict__ o_mid, const float* __restrict__ wo,
    float* __restrict__ opart)
{
  __shared__ float ws[32 * 73];                  // 9344 B
  __shared__ alignas(16) float xs[3 * 8 * 52];   // 4992 B
  const int y = blockIdx.x;
  const int half = blockIdx.y;
  const int cig = blockIdx.z;          // 8 ci per group
  const int tid = threadIdx.x;
  for (int idx = tid; idx < 3 * 8 * 50; idx += 128) {
    int ky = idx / (8 * 50);
    int r = idx - ky * (8 * 50);
    int cil = r / 50;
    int xx = r - cil * 50;
    int gy = y + ky - 1;
    int gx = xx - 1;
    float v = 0.0f;
    if (gy >= 0 && gy < H && (unsigned)gx < (unsigned)W)
      v = o_mid[(cig * 8 + cil) * HW + gy * W + gx];
    xs[(ky * 8 + cil) * 52 + xx] = v;
  }
  for (int idx = tid; idx < 32 * 72; idx += 128) {
    const int co_loc = idx / 72;
    const int e = idx - co_loc * 72;
    ws[co_loc * 73 + e] = wo[(half * 32 + co_loc) * (CMID * 9) + cig * 72 + e];
  }
  __syncthreads();

  const int col = tid >> 2;
  const int xg = tid & 3;
  const int co = half * 32 + col;
  const float* wrowb = &ws[col * 73];
  float acc[12];
#pragma unroll
  for (int i = 0; i < 12; ++i) acc[i] = 0.0f;

#pragma unroll 2
  for (int cil = 0; cil < 8; ++cil) {
#pragma unroll
    for (int ky = 0; ky < 3; ++ky) {
      const float4* p4 =
          reinterpret_cast<const float4*>(&xs[(ky * 8 + cil) * 52 + xg * 12]);
      float4 r0 = p4[0], r1 = p4[1], r2 = p4[2], r3 = p4[3];
      float xr[16] = {r0.x, r0.y, r0.z, r0.w, r1.x, r1.y, r1.z, r1.w,
                      r2.x, r2.y, r2.z, r2.w, r3.x, r3.y, r3.z, r3.w};
      const float* wr = wrowb + cil * 9 + ky * 3;
#pragma unroll
      for (int kx = 0; kx < 3; ++kx) {
        float wgt = wr[kx];
#pragma unroll
        for (int xx = 0; xx < 12; ++xx)
          acc[xx] = fmaf(wgt, xr[xx + kx], acc[xx]);
      }
    }
  }

  const int x0 = xg * 12;
  float* dst = &opart[(size_t)(cig * 64 + co) * HW + y * W + x0];
#pragma unroll
  for (int xx = 0; xx < 12; ++xx) dst[xx] = acc[xx];
}

// ---------------------------------------------------------------------------
// Kernel 3b (verified round 7-9): reduce 4 out-conv partials -> output.
// ---------------------------------------------------------------------------
__global__ __launch_bounds__(256) void out_reduce_kernel(
    const float* __restrict__ opart, float* __restrict__ out)
{
  const int fidx = blockIdx.x * 256 + threadIdx.x;  // 0..98303 (64ch*1536)
  const float4* src = reinterpret_cast<const float4*>(opart) + fidx;
  float4 s = src[0];
  const float4 s1 = src[64 * 1536], s2 = src[2 * 64 * 1536], s3 = src[3 * 64 * 1536];
  s.x += s1.x + s2.x + s3.x;
  s.y += s1.y + s2.y + s3.y;
  s.z += s1.z + s2.z + s3.z;
  s.w += s1.w + s2.w + s3.w;
  reinterpret_cast<float4*>(out)[fidx] = s;
}

// ---------------------------------------------------------------------------
extern "C" void kernel_launch(void* const* d_in, const int* in_sizes, int n_in,
                              void* d_out, int out_size, void* d_ws, size_t ws_size,
                              hipStream_t stream) {
  const float* x  = (const float*)d_in[0];
  const float* wq = (const float*)d_in[1];
  const float* bq = (const float*)d_in[2];
  const float* wk = (const float*)d_in[3];
  const float* bk = (const float*)d_in[4];
  const float* wv = (const float*)d_in[5];
  const float* bv = (const float*)d_in[6];
  const float* wo = (const float*)d_in[7];
  float* out = (float*)d_out;

  // ws layout (floats): q_s | k_s | v_s | o_mid | kvi | part | qpart(=opart)
  float* q_s   = (float*)d_ws;
  float* k_s   = q_s + QSSZ;
  float* v_s   = k_s + QSSZ;
  float* o_mid = v_s + QSSZ;
  float* kvi   = o_mid + QSSZ;
  float* part  = kvi + KVISZ;
  float* qpart = part + PARTSZ;
  float* opart = qpart;   // phases are stream-ordered; safe alias

  qkv_conv_kernel<<<dim3(128, 2, CIGQ), 192, 0, stream>>>(x, wq, wk, wv, qpart);
  qkv_reduce_kernel<<<dim3(576), 256, 0, stream>>>(qpart, bq, bk, bv,
                                                   q_s, k_s, v_s);
  kv_pack_kernel<<<dim3(45, 16), 128, 0, stream>>>(k_s, v_s, (float4*)kvi);
  attn_kernel<<<dim3(1536), 256, 0, stream>>>(q_s, (const float4*)kvi, part);
  merge_kernel<<<dim3(NQG, 16), 256, 0, stream>>>(part, o_mid);
  out_conv_kernel<<<dim3(128, 2, CIGO), 128, 0, stream>>>(o_mid, wo, opart);
  out_reduce_kernel<<<dim3(384), 256, 0, stream>>>(opart, out);
}